// Round 15
// baseline (149.892 us; speedup 1.0000x reference)
//
#include <hip/hip_runtime.h>
#include <hip/hip_fp16.h>
#include <stdint.h>

#define NF 64

#if defined(__has_builtin)
#  if __has_builtin(__builtin_amdgcn_fdot2)
#    define HAS_FDOT2 1
#  endif
#endif

typedef _Float16 half2v __attribute__((ext_vector_type(2)));
union H2 { int i; half2v v; __half2 h; float2 f_unused; };

// ---------------- single-pass ELL build (ELL inside d_out), XCD-windowed ----------------
__global__ __launch_bounds__(256) void k_ell(const int* __restrict__ src,
                                             const int* __restrict__ dst,
                                             int* degc, int* ocnt, int* oflow, int ocap,
                                             int* ell, int e, int n) {
    int grp = blockIdx.x & 7;
    int chunk = (n + 7) >> 3;
    int lo = grp * chunk;
    int hi = min(lo + chunk, n);
    int nb = gridDim.x >> 3;
    int bi = blockIdx.x >> 3;
    for (int i = bi * 256 + threadIdx.x; i < e; i += nb * 256) {
        int d = dst[i];
        if (d < lo || d >= hi) continue;
        int s = src[i];
        int slot = atomicAdd(&degc[d], 1);
        if (slot < NF) {
            ell[(unsigned)d * NF + slot] = s;
        } else {                                   // P(deg>64)~0; correctness fallback
            int o = atomicAdd(ocnt, 1);
            if (o < ocap) { oflow[2 * o] = s; oflow[2 * o + 1] = d; }
        }
    }
}

// ---------------- prescale to fp16: xh[row] = half(x[row] * rsqrt(deg+1)); row n = 0 ----------------
__global__ __launch_bounds__(256) void k_scale(const float* __restrict__ x,
                                               const int* __restrict__ degc,
                                               __half* __restrict__ xh, int n) {
    int i = blockIdx.x * 256 + threadIdx.x;      // float4 index (16 per row)
    int total = (n + 1) * (NF / 4);
    if (i >= total) return;
    int row = i >> 4;
    uint2 u = {0u, 0u};
    if (row < n) {
        float dd = rsqrtf((float)(degc[row] + 1));
        float4 v = reinterpret_cast<const float4*>(x)[i];
        __half2 p0 = __floats2half2_rn(v.x * dd, v.y * dd);
        __half2 p1 = __floats2half2_rn(v.z * dd, v.w * dd);
        u.x = *reinterpret_cast<unsigned*>(&p0);
        u.y = *reinterpret_cast<unsigned*>(&p1);
    }
    reinterpret_cast<uint2*>(xh)[i] = u;         // row n -> zero row
}

// ---------------- fused gather-aggregate + register-GEMM epilogue ----------------
// 1 node/wave. Gather: R14's 4 lane-groups x 16 lanes, fat uint2 loads.
// Epilogue: ZERO LDS -- lane j holds W[j][*] as 32 packed half2 in VGPRs;
// v broadcast by __shfl of packed half2; v_dot2_f32_f16 accumulate (f32).
// No __shared__, no barriers anywhere.

__global__ __launch_bounds__(256) void k_agg_gemm(const __half* __restrict__ xh,
                                                  const float* __restrict__ W,
                                                  const float* __restrict__ bias,
                                                  const int* __restrict__ degc,
                                                  float* out, int n) {
    unsigned lane = threadIdx.x & 63;
    int wv = threadIdx.x >> 6;
    unsigned grp = lane >> 4;          // 0..3: which edge of the quad
    unsigned fl  = lane & 15;          // feature-quad index: feats fl*4..fl*4+3
    float bj = bias[lane];

    // stage lane's W row into 32 packed half2 registers (one-time, 16KB/block)
    half2v w[32];
    {
        const float4* Wr = reinterpret_cast<const float4*>(W + (unsigned)lane * NF);
#pragma unroll
        for (int c = 0; c < 16; ++c) {
            float4 f = Wr[c];
            H2 u0; u0.h = __floats2half2_rn(f.x, f.y); w[2 * c] = u0.v;
            H2 u1; u1.h = __floats2half2_rn(f.z, f.w); w[2 * c + 1] = u1.v;
        }
    }

    const int* outi = (const int*)out;   // ELL aliased in out
    int ngroups = (n + 3) >> 2, gs = gridDim.x;
    int g = blockIdx.x;
    int d = g * 4 + wv;
    int ev = 0, mc = 0;
    if (d < n) {
        ev = outi[(unsigned)d * NF + lane];    // full-wave 256B ELL row
        mc = degc[d];
    }
    while (g < ngroups) {
        int gn = g + gs, dn = gn * 4 + wv;
        int evn = 0, mcn = 0;
        if (gn < ngroups && dn < n) {          // prefetch next iteration
            evn = outi[(unsigned)dn * NF + lane];
            mcn = degc[dn];
        }
        if (d < n) {
            float dd = rsqrtf((float)(mc + 1));
            int m = min(mc, NF);
            float a0 = 0.f, a1 = 0.f, a2 = 0.f, a3 = 0.f;   // 4 chains x 4 feats
            float b0 = 0.f, b1 = 0.f, b2 = 0.f, b3 = 0.f;
            float c0 = 0.f, c1 = 0.f, c2 = 0.f, c3 = 0.f;
            float e0 = 0.f, e1 = 0.f, e2 = 0.f, e3 = 0.f;
            for (int j = 0; j < m; j += 16) {  // 16 edges = 4 fat wave-loads
                int i0 = j + (int)grp, i1 = j + 4 + (int)grp;
                int i2 = j + 8 + (int)grp, i3 = j + 12 + (int)grp;
                int s0 = __shfl(ev, i0); s0 = (i0 < m) ? s0 : n;
                int s1 = __shfl(ev, i1); s1 = (i1 < m) ? s1 : n;
                int s2 = __shfl(ev, i2); s2 = (i2 < m) ? s2 : n;
                int s3 = __shfl(ev, i3); s3 = (i3 < m) ? s3 : n;
                uint2 u0 = *reinterpret_cast<const uint2*>(xh + (unsigned)s0 * NF + fl * 4);
                uint2 u1 = *reinterpret_cast<const uint2*>(xh + (unsigned)s1 * NF + fl * 4);
                uint2 u2 = *reinterpret_cast<const uint2*>(xh + (unsigned)s2 * NF + fl * 4);
                uint2 u3 = *reinterpret_cast<const uint2*>(xh + (unsigned)s3 * NF + fl * 4);
                float2 f;
                f = __half22float2(*reinterpret_cast<const __half2*>(&u0.x)); a0 += f.x; a1 += f.y;
                f = __half22float2(*reinterpret_cast<const __half2*>(&u0.y)); a2 += f.x; a3 += f.y;
                f = __half22float2(*reinterpret_cast<const __half2*>(&u1.x)); b0 += f.x; b1 += f.y;
                f = __half22float2(*reinterpret_cast<const __half2*>(&u1.y)); b2 += f.x; b3 += f.y;
                f = __half22float2(*reinterpret_cast<const __half2*>(&u2.x)); c0 += f.x; c1 += f.y;
                f = __half22float2(*reinterpret_cast<const __half2*>(&u2.y)); c2 += f.x; c3 += f.y;
                f = __half22float2(*reinterpret_cast<const __half2*>(&u3.x)); e0 += f.x; e1 += f.y;
                f = __half22float2(*reinterpret_cast<const __half2*>(&u3.y)); e2 += f.x; e3 += f.y;
            }
            // self term (prescaled row d)
            uint2 us = *reinterpret_cast<const uint2*>(xh + (unsigned)d * NF + fl * 4);
            float2 fs0 = __half22float2(*reinterpret_cast<const __half2*>(&us.x));
            float2 fs1 = __half22float2(*reinterpret_cast<const __half2*>(&us.y));
            a0 = (a0 + b0) + (c0 + e0);
            a1 = (a1 + b1) + (c1 + e1);
            a2 = (a2 + b2) + (c2 + e2);
            a3 = (a3 + b3) + (c3 + e3);
            // combine 4 edge-groups: after xor16+xor32 EVERY lane holds the full sums
            a0 += __shfl_xor(a0, 16); a1 += __shfl_xor(a1, 16);
            a2 += __shfl_xor(a2, 16); a3 += __shfl_xor(a3, 16);
            a0 += __shfl_xor(a0, 32); a1 += __shfl_xor(a1, 32);
            a2 += __shfl_xor(a2, 32); a3 += __shfl_xor(a3, 32);
            // lane holds v[fl*4 .. fl*4+3]; pack to half2 for broadcast
            H2 hv0, hv1;
            hv0.h = __floats2half2_rn(dd * (a0 + fs0.x), dd * (a1 + fs0.y));
            hv1.h = __floats2half2_rn(dd * (a2 + fs1.x), dd * (a3 + fs1.y));
            int iv0 = hv0.i, iv1 = hv1.i;
            // register GEMM: r = bias + sum_c dot2(v[4c..], W[lane][4c..])
            float r = bj;
#pragma unroll
            for (int c = 0; c < 16; ++c) {
                H2 p0, p1;
                p0.i = __shfl(iv0, c);         // v[4c], v[4c+1] (lane c holds fl==c)
                p1.i = __shfl(iv1, c);         // v[4c+2], v[4c+3]
#ifdef HAS_FDOT2
                r = __builtin_amdgcn_fdot2(p0.v, w[2 * c], r, false);
                r = __builtin_amdgcn_fdot2(p1.v, w[2 * c + 1], r, false);
#else
                {
                    float2 av = __half22float2(p0.h);
                    H2 wb0; wb0.v = w[2 * c];
                    float2 bv = __half22float2(wb0.h);
                    r = fmaf(av.x, bv.x, r); r = fmaf(av.y, bv.y, r);
                    av = __half22float2(p1.h);
                    H2 wb1; wb1.v = w[2 * c + 1];
                    bv = __half22float2(wb1.h);
                    r = fmaf(av.x, bv.x, r); r = fmaf(av.y, bv.y, r);
                }
#endif
            }
            out[(unsigned)d * NF + lane] = r;
        }
        g = gn; d = dn; ev = evn; mc = mcn;
    }
}

// ---------------- overflow fixup (post-GEMM, by linearity; exact fp32 path) ----------------
__global__ __launch_bounds__(64) void k_oflow(const float* __restrict__ x,
                                              const float* __restrict__ W,
                                              const int* __restrict__ degc,
                                              const int* __restrict__ ocnt,
                                              const int* __restrict__ oflow, int ocap,
                                              float* out) {
    int c = *ocnt; if (c > ocap) c = ocap;
    int lane = threadIdx.x;
    for (int o = blockIdx.x; o < c; o += gridDim.x) {
        int s = oflow[2 * o], d = oflow[2 * o + 1];
        float norm = rsqrtf((float)(degc[s] + 1)) * rsqrtf((float)(degc[d] + 1));
        float r = 0.f;
        for (int k = 0; k < NF; ++k)
            r = fmaf(x[(long)s * NF + k], W[lane * NF + k], r);
        atomicAdd(&out[(long)d * NF + lane], norm * r);
    }
}

// ---------------- launch ----------------

extern "C" void kernel_launch(void* const* d_in, const int* in_sizes, int n_in,
                              void* d_out, int out_size, void* d_ws, size_t ws_size,
                              hipStream_t stream) {
    const float* x    = (const float*)d_in[0];
    const int*   ei   = (const int*)d_in[1];   // harness pushes integers as int32
    const float* W    = (const float*)d_in[2];
    const float* bias = (const float*)d_in[3];
    float*       out  = (float*)d_out;

    const int n = in_sizes[0] / NF;       // 100000
    const int e = in_sizes[1] / 2;        // 1250000
    const int* src = ei;
    const int* dst = ei + e;

    // ws layout: degc n | ocnt 1 | align | xh (n+1)*64 halfs | oflow rest
    int*    degc = (int*)d_ws;
    int*    ocnt = degc + n;
    uintptr_t p = ((uintptr_t)(ocnt + 1) + 255) & ~(uintptr_t)255;
    __half* xh   = (__half*)p;
    int*    oflow = (int*)(xh + (size_t)(n + 1) * NF);
    long    rest = (long)ws_size - ((char*)oflow - (char*)d_ws);
    int     ocap = rest > 0 ? (int)(rest / 8) : 0;

    dim3 blk(256);
    hipMemsetAsync(degc, 0, (size_t)(n + 1) * sizeof(int), stream);  // degc + ocnt
    k_ell  <<<2048, blk, 0, stream>>>(src, dst, degc, ocnt, oflow, ocap, (int*)out, e, n);
    int total4 = (n + 1) * (NF / 4);
    k_scale<<<(total4 + 255) / 256, blk, 0, stream>>>(x, degc, xh, n);
    k_agg_gemm<<<2048, blk, 0, stream>>>(xh, W, bias, degc, out, n);
    k_oflow<<<64, 64, 0, stream>>>(x, W, degc, ocnt, oflow, ocap, out);
}